// Round 7
// baseline (694.943 us; speedup 1.0000x reference)
//
#include <hip/hip_runtime.h>

// CodebookQuantizer: out[q] = softmax_k( (2*h[q].cb[k] - |cb[k]|^2) / T ) @ cb
// B*Q = 16384, D = 512, K = 8192, T = 0.1. Output fp32 (z_e forward value).
//
// K1cb: codebook fp32 -> pre-swizzled bf16 + exact e_sq (d_ws).
// K1h:  h fp32 -> bf16 MFMA B-fragment planes (d_ws), if scratch allows.
// K2:   1024 blocks = 128 q-tiles x 8 code octants (octant = bid&7 -> L2-
//       pinned 1 MB slice/XCD). 256 thr = 4 waves x 32 q-rows. bf16 MFMA
//       approx logits; per (row,octant) sub-list: 8 protected slots (top-2
//       per owning lane, register-tracked, MAIN LOOP ONLY - the prepass must
//       not track or it duplicates chunk-0 tops) + 8-slot ring of hits.
// K3:   merge 8 sub-lists/row, dedup every slot against earlier protected
//       slots, prune at max-44, exact fp32 recompute + online softmax gather.

typedef short  bf16x8 __attribute__((ext_vector_type(8)));
typedef float  f32x4  __attribute__((ext_vector_type(4)));

#define BQ      128           // q rows per block
#define KC      16            // codebook rows per chunk
#define DD      512
#define NCODES  8192
#define NOCT    8
#define OCODES  (NCODES / NOCT)     // 1024
#define NCHUNK  (OCODES / KC)       // 64
#define NSUB    8                   // sub-lists per row
#define CAPS    16                  // slots per sub-list
#define NPROT   8                   // protected slots (4 lanes x top-2)
#define TH2     34.0f               // scan append threshold (log2 units)
#define PRUNE   44.0f               // merge prune threshold (log2 units)

// 2/T * log2(e), 1/T * log2(e)
#define SC_CROSS 28.853900817779268f
#define SC_ESQ   14.426950408889634f

#define SZ_CBSWZ ((size_t)NCODES * DD * 2)          // 8 MB
#define SZ_ESQ   ((size_t)NCODES * 4)               // 32 KB
#define SZ_WLIST ((size_t)16384 * NSUB * CAPS * 4)  // 8 MB
#define SZ_WCNT  ((size_t)16384 * NSUB * 4)         // 512 KB
#define SZ_HSWZ  ((size_t)512 * 16 * 2 * 64 * 16)   // 16 MB

static __device__ __forceinline__ unsigned short f2bf(float x) {
    unsigned int u = __float_as_uint(x);
    u += 0x7fffu + ((u >> 16) & 1u);
    return (unsigned short)(u >> 16);
}
static __device__ __forceinline__ unsigned int packE(float L, int code) {
    return ((unsigned int)f2bf(L) << 16) | (unsigned int)code;
}

static __device__ __forceinline__ void gload_lds16(const void* g, void* l) {
    __builtin_amdgcn_global_load_lds(
        (const __attribute__((address_space(1))) unsigned int*)g,
        (__attribute__((address_space(3))) unsigned int*)l, 16, 0, 0);
}
static __device__ __forceinline__ void gload_lds4(const void* g, void* l) {
    __builtin_amdgcn_global_load_lds(
        (const __attribute__((address_space(1))) unsigned int*)g,
        (__attribute__((address_space(3))) unsigned int*)l, 4, 0, 0);
}

// ---------------- K1cb: codebook -> pre-swizzled bf16 + e_sq ----------------
__global__ __launch_bounds__(256)
void vq_convert_cb(const float* __restrict__ cb,
                   unsigned short* __restrict__ cbswz,
                   float* __restrict__ esq)
{
    const int w     = threadIdx.x >> 6;
    const int lane  = threadIdx.x & 63;
    const int rbase = blockIdx.x * 32 + w * 8;
#pragma unroll 1
    for (int i = 0; i < 8; ++i) {
        const int r = rbase + i;
        const float* src = cb + (size_t)r * DD + lane * 8;
        float4 a = *reinterpret_cast<const float4*>(src);
        float4 b = *reinterpret_cast<const float4*>(src + 4);
        float v[8] = {a.x, a.y, a.z, a.w, b.x, b.y, b.z, b.w};
        float s2 = 0.f;
        bf16x8 o;
#pragma unroll
        for (int j = 0; j < 8; ++j) { s2 += v[j] * v[j]; o[j] = (short)f2bf(v[j]); }
#pragma unroll
        for (int off = 32; off > 0; off >>= 1) s2 += __shfl_xor(s2, off);
        const int u = lane ^ (r & 7);   // pre-swizzle: linear LDS copy lands swizzled
        *reinterpret_cast<bf16x8*>(cbswz + (size_t)r * DD + u * 8) = o;
        if (lane == 0) esq[r] = s2;
    }
}

// ---------------- K1h: h -> bf16 B-fragment planes ----------------
__global__ __launch_bounds__(256)
void vq_convert_h(const float* __restrict__ h,
                  unsigned short* __restrict__ hswz)
{
    const int slice = blockIdx.x;
    const int w     = threadIdx.x >> 6;
    const int lane  = threadIdx.x & 63;
#pragma unroll
    for (int i = 0; i < 4; ++i) {
        const int k = w * 4 + i;
#pragma unroll
        for (int half = 0; half < 2; ++half) {
            const int row = slice * 32 + half * 16 + (lane & 15);
            const int d0  = k * 32 + (lane >> 4) * 8;
            const float* src = h + (size_t)row * DD + d0;
            float4 a = *reinterpret_cast<const float4*>(src);
            float4 b = *reinterpret_cast<const float4*>(src + 4);
            bf16x8 f;
            f[0]=(short)f2bf(a.x); f[1]=(short)f2bf(a.y); f[2]=(short)f2bf(a.z); f[3]=(short)f2bf(a.w);
            f[4]=(short)f2bf(b.x); f[5]=(short)f2bf(b.y); f[6]=(short)f2bf(b.z); f[7]=(short)f2bf(b.w);
            *reinterpret_cast<bf16x8*>(
                hswz + ((((size_t)slice * 16 + k) * 2 + half) * 64 + lane) * 8) = f;
        }
    }
}

// ---------------- K2: scan one octant for 128 q rows ----------------
template <bool PRE>
__global__ __launch_bounds__(256, 3)
void vq_scan_kernel(const float* __restrict__ h,
                    const unsigned short* __restrict__ cbswz,
                    const float* __restrict__ esqg,
                    const unsigned short* __restrict__ hswz,
                    unsigned int* __restrict__ wlist,
                    unsigned int* __restrict__ wcnt)
{
    __shared__ __align__(16) unsigned short sC[2][KC * DD];  // 32 KB dbuf
    __shared__ __align__(16) float sEsq[2][KC];
    __shared__ int sCnt[BQ];

    const int tid  = threadIdx.x;
    const int w    = tid >> 6;          // wave 0..3, owns q rows [w*32, w*32+32)
    const int lane = tid & 63;
    const int c16  = lane & 15;
    const int ub   = lane >> 4;
    const int bid  = blockIdx.x;
    const int oct  = bid & 7;           // code octant (constant per XCD)
    const int qt   = bid >> 3;          // q tile (128)
    const int qb   = qt * BQ;
    const int g0   = oct * OCODES;      // first global code of octant
    const int slice = qt * 4 + w;

    if (tid < BQ) sCnt[tid] = NPROT;

    // ---- H B-fragments: rows qb+w*32+c16 (A) and +16 (B) ----
    bf16x8 hfA[16], hfB[16];
    if (PRE) {
        const bf16x8* hs = (const bf16x8*)hswz;
#pragma unroll
        for (int k = 0; k < 16; ++k) {
            hfA[k] = hs[(((size_t)slice * 16 + k) * 2 + 0) * 64 + lane];
            hfB[k] = hs[(((size_t)slice * 16 + k) * 2 + 1) * 64 + lane];
        }
    } else {
        const int qrowA = qb + w * 32 + c16;
        const int dsub  = ub * 8;
#pragma unroll
        for (int k = 0; k < 16; ++k) {
            const float* sA = h + (size_t)qrowA * DD + k * 32 + dsub;
            const float* sB = sA + (size_t)16 * DD;
            float4 a0 = *reinterpret_cast<const float4*>(sA);
            float4 a1 = *reinterpret_cast<const float4*>(sA + 4);
            float4 b0 = *reinterpret_cast<const float4*>(sB);
            float4 b1 = *reinterpret_cast<const float4*>(sB + 4);
            bf16x8 fa, fb;
            fa[0]=(short)f2bf(a0.x); fa[1]=(short)f2bf(a0.y); fa[2]=(short)f2bf(a0.z); fa[3]=(short)f2bf(a0.w);
            fa[4]=(short)f2bf(a1.x); fa[5]=(short)f2bf(a1.y); fa[6]=(short)f2bf(a1.z); fa[7]=(short)f2bf(a1.w);
            fb[0]=(short)f2bf(b0.x); fb[1]=(short)f2bf(b0.y); fb[2]=(short)f2bf(b0.z); fb[3]=(short)f2bf(b0.w);
            fb[4]=(short)f2bf(b1.x); fb[5]=(short)f2bf(b1.y); fb[6]=(short)f2bf(b1.z); fb[7]=(short)f2bf(b1.w);
            hfA[k] = fa; hfB[k] = fb;
        }
    }

    const int rowlocA = w * 32 + c16;
    const int rowlocB = rowlocA + 16;
    const size_t lbA  = ((size_t)(qb + rowlocA) * NSUB + oct) * CAPS;
    const size_t lbB  = ((size_t)(qb + rowlocB) * NSUB + oct) * CAPS;

    float mrunA = -1e38f, mrunB = -1e38f;
    // per-lane top-2 over this lane's private code stream (4 codes/chunk/row)
    float b1LA = -1e38f, b2LA = -1e38f, b1LB = -1e38f, b2LB = -1e38f;
    int   b1CA = 0, b2CA = 0, b1CB = 0, b2CB = 0;

    const int swz    = c16 & 7;
    const int clocal = ub * 4;

    // stage chunk ct into buffer b: 16 KB = 256 threads x 4 x 16 B
    auto stage = [&](int b, int ct) {
        const char* gc = (const char*)cbswz + ((size_t)g0 + (size_t)ct * KC) * (DD * 2);
#pragma unroll
        for (int r = 0; r < 4; ++r)
            gload_lds16(gc + r * 4096 + tid * 16,
                        (char*)&sC[b][0] + r * 4096 + tid * 16);
        if (w == 0 && lane < KC)
            gload_lds4((const char*)(esqg + g0 + ct * KC) + lane * 4,
                       (char*)&sEsq[b][0]);
    };

    // track=false for the prepass: chunk 0 is re-scanned at t=0 with track=true;
    // tracking twice would make b2 a duplicate of b1 (the round-6 bug).
    auto scan_chunk = [&](int cur, int gbase, bool append, bool track) {
        const float thrA = mrunA - TH2, thrB = mrunB - TH2;
        const unsigned short* cbase = &sC[cur][c16 * DD];
        f32x4 aA0 = {0,0,0,0}, aA1 = {0,0,0,0}, aB0 = {0,0,0,0}, aB1 = {0,0,0,0};
#pragma unroll
        for (int k = 0; k < 16; k += 2) {
            bf16x8 a0 = *reinterpret_cast<const bf16x8*>(&cbase[(((k    ) * 4 + ub) ^ swz) * 8]);
            bf16x8 a1 = *reinterpret_cast<const bf16x8*>(&cbase[(((k + 1) * 4 + ub) ^ swz) * 8]);
            aA0 = __builtin_amdgcn_mfma_f32_16x16x32_bf16(a0, hfA[k],     aA0, 0, 0, 0);
            aB0 = __builtin_amdgcn_mfma_f32_16x16x32_bf16(a0, hfB[k],     aB0, 0, 0, 0);
            aA1 = __builtin_amdgcn_mfma_f32_16x16x32_bf16(a1, hfA[k + 1], aA1, 0, 0, 0);
            aB1 = __builtin_amdgcn_mfma_f32_16x16x32_bf16(a1, hfB[k + 1], aB1, 0, 0, 0);
        }
        f32x4 e4 = *reinterpret_cast<const f32x4*>(&sEsq[cur][clocal]);
        float LvA[4], LvB[4];
#pragma unroll
        for (int r = 0; r < 4; ++r) {
            LvA[r] = (aA0[r] + aA1[r]) * SC_CROSS - e4[r] * SC_ESQ;
            LvB[r] = (aB0[r] + aB1[r]) * SC_CROSS - e4[r] * SC_ESQ;
        }
        if (track) {
#pragma unroll
            for (int r = 0; r < 4; ++r) {
                const int cd = gbase + clocal + r;
                if (LvA[r] > b1LA)      { b2LA = b1LA; b2CA = b1CA; b1LA = LvA[r]; b1CA = cd; }
                else if (LvA[r] > b2LA) { b2LA = LvA[r]; b2CA = cd; }
                if (LvB[r] > b1LB)      { b2LB = b1LB; b2CB = b1CB; b1LB = LvB[r]; b1CB = cd; }
                else if (LvB[r] > b2LB) { b2LB = LvB[r]; b2CB = cd; }
            }
        }
        if (append) {
            if (LvA[0] > thrA || LvA[1] > thrA || LvA[2] > thrA || LvA[3] > thrA) {
#pragma unroll
                for (int r = 0; r < 4; ++r)
                    if (LvA[r] > thrA) {
                        int idx  = atomicAdd(&sCnt[rowlocA], 1);
                        int slot = idx < CAPS ? idx : NPROT + ((idx - NPROT) & (NPROT - 1));
                        wlist[lbA + slot] = packE(LvA[r], gbase + clocal + r);
                    }
            }
            if (LvB[0] > thrB || LvB[1] > thrB || LvB[2] > thrB || LvB[3] > thrB) {
#pragma unroll
                for (int r = 0; r < 4; ++r)
                    if (LvB[r] > thrB) {
                        int idx  = atomicAdd(&sCnt[rowlocB], 1);
                        int slot = idx < CAPS ? idx : NPROT + ((idx - NPROT) & (NPROT - 1));
                        wlist[lbB + slot] = packE(LvB[r], gbase + clocal + r);
                    }
            }
        }
        float mlA = fmaxf(fmaxf(LvA[0], LvA[1]), fmaxf(LvA[2], LvA[3]));
        float mlB = fmaxf(fmaxf(LvB[0], LvB[1]), fmaxf(LvB[2], LvB[3]));
        mlA = fmaxf(mlA, __shfl_xor(mlA, 16)); mlA = fmaxf(mlA, __shfl_xor(mlA, 32));
        mlB = fmaxf(mlB, __shfl_xor(mlB, 16)); mlB = fmaxf(mlB, __shfl_xor(mlB, 32));
        mrunA = fmaxf(mrunA, mlA);
        mrunB = fmaxf(mrunB, mlB);
    };

    // prologue: stage chunk 0; prime running max (no append, NO top-2 tracking)
    stage(0, 0);
    __syncthreads();
    scan_chunk(0, g0, false, false);

    int cur = 0;
    for (int t = 0; t < NCHUNK; ++t) {
        if (t + 1 < NCHUNK) stage(cur ^ 1, t + 1);
        scan_chunk(cur, g0 + t * KC, true, true);
        __syncthreads();   // next-chunk DMA drained; buf[cur] reads complete
        cur ^= 1;
    }

    // protected slots: each owning lane writes its top-2 (slots 2*ub, 2*ub+1)
    wlist[lbA + ub * 2]     = packE(b1LA, b1CA);
    wlist[lbA + ub * 2 + 1] = packE(b2LA, b2CA);
    wlist[lbB + ub * 2]     = packE(b1LB, b1CB);
    wlist[lbB + ub * 2 + 1] = packE(b2LB, b2CB);

    if (tid < BQ) wcnt[(size_t)(qb + tid) * NSUB + oct] = (unsigned)sCnt[tid];
}

// ---------------- K3: merge sub-lists, dedup, prune, exact softmax gather --------
__global__ __launch_bounds__(512)
void vq_merge_kernel(const float* __restrict__ h,
                     const float* __restrict__ cb,
                     const unsigned int* __restrict__ wlist,
                     const unsigned int* __restrict__ wcnt,
                     float* __restrict__ out)
{
    const int w    = threadIdx.x >> 6;
    const int lane = threadIdx.x & 63;
    const int qg   = blockIdx.x * 8 + w;

    const int sl = lane >> 3;           // sub-list 0..7
    const int s0 = (lane & 7) * 2;      // slots s0, s0+1 (pair entirely prot or ring)
    const size_t base = ((size_t)qg * NSUB + sl) * CAPS;
    const unsigned cnt   = wcnt[(size_t)qg * NSUB + sl];
    const unsigned limit = cnt < (unsigned)CAPS ? cnt : (unsigned)CAPS;

    uint2 e2 = *reinterpret_cast<const uint2*>(&wlist[base + s0]);
    int   code0 = e2.x & 0xFFFF, code1 = e2.y & 0xFFFF;
    float L0 = __uint_as_float(e2.x & 0xFFFF0000u);
    float L1 = __uint_as_float(e2.y & 0xFFFF0000u);
    bool v0 = (unsigned)s0 < limit;
    bool v1 = (unsigned)(s0 + 1) < limit;

    // dedup: a slot is invalid if its code appears in an EARLIER protected slot
    // (ring slots check all 8 protected; protected pair s0 checks slots < s0,
    // and code1 additionally checks code0). Robust to any upstream duplicate.
    {
        uint4 p0 = *reinterpret_cast<const uint4*>(&wlist[base]);
        uint4 p1 = *reinterpret_cast<const uint4*>(&wlist[base + 4]);
        const unsigned pc[8] = {p0.x & 0xFFFFu, p0.y & 0xFFFFu, p0.z & 0xFFFFu, p0.w & 0xFFFFu,
                                p1.x & 0xFFFFu, p1.y & 0xFFFFu, p1.z & 0xFFFFu, p1.w & 0xFFFFu};
        const int lim0 = (s0 >= NPROT) ? 8 : s0;
        bool d0 = false, d1 = false;
#pragma unroll
        for (int j = 0; j < 8; ++j) {
            d0 |= (j < lim0) && ((unsigned)code0 == pc[j]);
            d1 |= (j < lim0) && ((unsigned)code1 == pc[j]);
        }
        d1 |= (code1 == code0) && (s0 < NPROT);
        v0 &= !d0; v1 &= !d1;
    }

    float m = fmaxf(v0 ? L0 : -1e38f, v1 ? L1 : -1e38f);
#pragma unroll
    for (int off = 1; off < 64; off <<= 1) m = fmaxf(m, __shfl_xor(m, off));
    const float thr = m - PRUNE;
    unsigned long long mask0 = __ballot(v0 && L0 > thr);
    unsigned long long mask1 = __ballot(v1 && L1 > thr);

    float hreg[8];
    const float* hp = h + (size_t)qg * DD + lane * 8;
#pragma unroll
    for (int j = 0; j < 8; ++j) hreg[j] = hp[j];

    float Mex = -1e38f, lsum = 0.f;
    float acc[8] = {0.f,0.f,0.f,0.f,0.f,0.f,0.f,0.f};

    auto process = [&](unsigned long long mask, int codev) {
#pragma unroll 1
        while (mask) {
            const int s = __builtin_ctzll(mask);
            mask &= mask - 1;
            const int code = __shfl(codev, s);
            const float* cp = cb + (size_t)code * DD + lane * 8;
            float c[8];
            float dot = 0.f, s2 = 0.f;
#pragma unroll
            for (int j = 0; j < 8; ++j) {
                c[j] = cp[j];
                dot += hreg[j] * c[j];
                s2  += c[j] * c[j];
            }
#pragma unroll
            for (int off = 32; off > 0; off >>= 1) {
                dot += __shfl_xor(dot, off);
                s2  += __shfl_xor(s2,  off);
            }
            const float Lex = dot * SC_CROSS - s2 * SC_ESQ;   // exact log2-logit
            const float mn  = fmaxf(Mex, Lex);
            const float f   = exp2f(Mex - mn);
            const float wj  = exp2f(Lex - mn);
            lsum = lsum * f + wj;
#pragma unroll
            for (int j = 0; j < 8; ++j) acc[j] = acc[j] * f + wj * c[j];
            Mex = mn;
        }
    };
    process(mask0, code0);
    process(mask1, code1);

    const float inv = 1.0f / lsum;
    float* op = out + (size_t)qg * DD + lane * 8;
    float4 o0 = {acc[0]*inv, acc[1]*inv, acc[2]*inv, acc[3]*inv};
    float4 o1 = {acc[4]*inv, acc[5]*inv, acc[6]*inv, acc[7]*inv};
    *reinterpret_cast<float4*>(op)     = o0;
    *reinterpret_cast<float4*>(op + 4) = o1;
}

extern "C" void kernel_launch(void* const* d_in, const int* in_sizes, int n_in,
                              void* d_out, int out_size, void* d_ws, size_t ws_size,
                              hipStream_t stream) {
    const float* h  = (const float*)d_in[0];   // (16384, 512) fp32
    const float* cb = (const float*)d_in[1];   // (8192, 512) fp32
    float* out = (float*)d_out;                // (16384, 512) fp32

    // ws layout: cbswz | esq | wlist | wcnt | [hswz]
    char* p = (char*)d_ws;
    unsigned short* cbswz = (unsigned short*)p;  p += SZ_CBSWZ;
    float*          esq   = (float*)p;           p += SZ_ESQ;
    unsigned int*   wlist = (unsigned int*)p;    p += SZ_WLIST;
    unsigned int*   wcnt  = (unsigned int*)p;    p += SZ_WCNT;
    unsigned short* hswz  = (unsigned short*)p;

    const size_t need_full = SZ_CBSWZ + SZ_ESQ + SZ_WLIST + SZ_WCNT + SZ_HSWZ;
    const bool pre = ws_size >= need_full;

    vq_convert_cb<<<dim3(NCODES / 32), dim3(256), 0, stream>>>(cb, cbswz, esq);
    if (pre) {
        vq_convert_h<<<dim3(512), dim3(256), 0, stream>>>(h, hswz);
        vq_scan_kernel<true><<<dim3(1024), dim3(256), 0, stream>>>(
            h, cbswz, esq, hswz, wlist, wcnt);
    } else {
        vq_scan_kernel<false><<<dim3(1024), dim3(256), 0, stream>>>(
            h, cbswz, esq, nullptr, wlist, wcnt);
    }
    vq_merge_kernel<<<dim3(16384 / 8), dim3(512), 0, stream>>>(h, cb, wlist, wcnt, out);
}

// Round 10
// 338.293 us; speedup vs baseline: 2.0543x; 2.0543x over previous
//
#include <hip/hip_runtime.h>

// CodebookQuantizer: out[q] = softmax_k( (2*h[q].cb[k] - |cb[k]|^2) / T ) @ cb
// B*Q = 16384, D = 512, K = 8192, T = 0.1. Output fp32 (z_e forward value).
//
// fp8-e4m3 MFMA scan (16x16x32_fp8_fp8). fp8 halves LDS bytes AND H-register
// bytes -> one wave owns 64 q rows at ~128 VGPR of H; LDS traffic/CU 4x lower
// than the bf16 r4 design.
// K1: codebook fp32 -> fp8, frag-permuted + XOR-swizzled units, + esq*SC_ESQ.
// K2: 512 blocks = 64 q-tiles x 8 octants (512KB slice L2-pinned per XCD);
//     256 thr = 4 waves x 64 q. Approx logits; per (row,octant) sub-list:
//     8 protected slots (top-2 per owning lane, register-tracked, main loop
//     only) + 8-slot ring. Weight-relevant codes (within ~25 log2 of max)
//     are always in-lane top-2 (in-lane spacing ~6000 >> fp8 noise 47).
// K3: merge 8 sub-lists, dedup, prune at max-360 (= 25 weight window +
//     6 sigma fp8 pair noise + bf16 packing; round-9 bug was PRUNE=150,
//     only 2.7 sigma -> pruned relevant codes), exact fp32 softmax gather.

typedef float          f32x4 __attribute__((ext_vector_type(4)));
typedef unsigned long  u64x2 __attribute__((ext_vector_type(2)));

#define BQ      256
#define KC      64
#define DD      512
#define NCODES  8192
#define NOCT    8
#define OCODES  (NCODES / NOCT)   // 1024
#define NCHUNK  (OCODES / KC)     // 16
#define NSUB    8
#define CAPS    16
#define NPROT   8
#define TH2     170.0f            // scan append threshold (log2 units)
#define PRUNE   360.0f            // merge prune threshold (log2 units, 6-sigma)

#define SC_CROSS 28.853900817779268f   // 2/T*log2(e)
#define SC_ESQ   14.426950408889634f   // 1/T*log2(e)

#define SZ_CBF8  ((size_t)NCODES * DD)              // 4 MB
#define SZ_ESQ   ((size_t)NCODES * 4)               // 32 KB
#define SZ_WLIST ((size_t)16384 * NSUB * CAPS * 4)  // 8.4 MB
#define SZ_WCNT  ((size_t)16384 * NSUB * 4)         // 512 KB

static __device__ __forceinline__ unsigned short f2bf(float x) {
    unsigned int u = __float_as_uint(x);
    u += 0x7fffu + ((u >> 16) & 1u);
    return (unsigned short)(u >> 16);
}
static __device__ __forceinline__ unsigned int packE(float L, int code) {
    return ((unsigned int)f2bf(L) << 16) | (unsigned int)code;
}
// word-select must be a literal constant -> template parameter
template <bool HI>
static __device__ __forceinline__ unsigned int pk8(float a, float b, unsigned int old) {
    return __builtin_amdgcn_cvt_pk_fp8_f32(a, b, (int)old, HI);
}
static __device__ __forceinline__ f32x4 mfma8(unsigned long a, unsigned long b, f32x4 c) {
    return __builtin_amdgcn_mfma_f32_16x16x32_fp8_fp8((long)a, (long)b, c, 0, 0, 0);
}
static __device__ __forceinline__ void gload_lds16(const void* g, void* l) {
    __builtin_amdgcn_global_load_lds(
        (const __attribute__((address_space(1))) unsigned int*)g,
        (__attribute__((address_space(3))) unsigned int*)l, 16, 0, 0);
}
static __device__ __forceinline__ void gload_lds4(const void* g, void* l) {
    __builtin_amdgcn_global_load_lds(
        (const __attribute__((address_space(1))) unsigned int*)g,
        (__attribute__((address_space(3))) unsigned int*)l, 4, 0, 0);
}

// ---- K1: codebook -> fp8 frag-permuted units + pre-scaled e_sq ----
// Row r (512 B) = 32 units of 16 B. Logical unit u = p*4+g holds ksteps
// (2p,2p+1) for lane-group g: bytes 0..7 = k(64p+8g..+7), 8..15 = +32.
// Stored at position (u ^ (r&7)) for bank spread; K2 reads with same XOR.
__global__ __launch_bounds__(256)
void vq_convert_cb(const float* __restrict__ cb,
                   unsigned char* __restrict__ cbf8,
                   float* __restrict__ esqp)
{
    const int r = blockIdx.x * 8 + (threadIdx.x >> 5);
    const int u = threadIdx.x & 31;
    const int p = u >> 2, g = u & 3;
    const int k0 = p * 64 + g * 8;
    const float* src = cb + (size_t)r * DD;
    float4 a0 = *reinterpret_cast<const float4*>(src + k0);
    float4 a1 = *reinterpret_cast<const float4*>(src + k0 + 4);
    float4 b0 = *reinterpret_cast<const float4*>(src + k0 + 32);
    float4 b1 = *reinterpret_cast<const float4*>(src + k0 + 36);
    unsigned int w0 = pk8<false>(a0.x, a0.y, 0); w0 = pk8<true>(a0.z, a0.w, w0);
    unsigned int w1 = pk8<false>(a1.x, a1.y, 0); w1 = pk8<true>(a1.z, a1.w, w1);
    unsigned int w2 = pk8<false>(b0.x, b0.y, 0); w2 = pk8<true>(b0.z, b0.w, w2);
    unsigned int w3 = pk8<false>(b1.x, b1.y, 0); w3 = pk8<true>(b1.z, b1.w, w3);
    float s2 = a0.x*a0.x + a0.y*a0.y + a0.z*a0.z + a0.w*a0.w
             + a1.x*a1.x + a1.y*a1.y + a1.z*a1.z + a1.w*a1.w
             + b0.x*b0.x + b0.y*b0.y + b0.z*b0.z + b0.w*b0.w
             + b1.x*b1.x + b1.y*b1.y + b1.z*b1.z + b1.w*b1.w;
#pragma unroll
    for (int off = 16; off > 0; off >>= 1) s2 += __shfl_xor(s2, off);
    if (u == 0) esqp[r] = s2 * SC_ESQ;
    uint4 o = {w0, w1, w2, w3};
    *reinterpret_cast<uint4*>(cbf8 + (size_t)r * DD + (u ^ (r & 7)) * 16) = o;
}

// ---- K2: fp8 scan, one octant x 256 q rows per block ----
__global__ __launch_bounds__(256, 2)
void vq_scan_kernel(const float* __restrict__ h,
                    const unsigned char* __restrict__ cbf8,
                    const float* __restrict__ esqp,
                    unsigned int* __restrict__ wlist,
                    unsigned int* __restrict__ wcnt)
{
    __shared__ __align__(16) unsigned char sC[2][KC * DD];   // 64 KB dbuf
    __shared__ __align__(16) float sEsq[2][KC];
    __shared__ int sCnt[BQ];

    const int tid  = threadIdx.x;
    const int w    = tid >> 6;          // wave 0..3, owns q [w*64, w*64+64)
    const int lane = tid & 63;
    const int c16  = lane & 15;
    const int ub   = lane >> 4;
    const int oct  = blockIdx.x & 7;    // constant per XCD -> slice L2-pinned
    const int qt   = blockIdx.x >> 3;
    const int qb   = qt * BQ;
    const int g0   = oct * OCODES;

    if (tid < BQ) sCnt[tid] = NPROT;

    // ---- inline h -> fp8 B-fragments: hf[cg][s], cg = q col-group ----
    unsigned long hf[4][16];
#pragma unroll
    for (int cg = 0; cg < 4; ++cg) {
        const size_t qrow = (size_t)(qb + w * 64 + cg * 16 + c16);
#pragma unroll
        for (int s = 0; s < 16; ++s) {
            const float* src = h + qrow * DD + s * 32 + ub * 8;
            float4 x = *reinterpret_cast<const float4*>(src);
            float4 y = *reinterpret_cast<const float4*>(src + 4);
            unsigned int lo = pk8<false>(x.x, x.y, 0); lo = pk8<true>(x.z, x.w, lo);
            unsigned int hi = pk8<false>(y.x, y.y, 0); hi = pk8<true>(y.z, y.w, hi);
            hf[cg][s] = (unsigned long)lo | ((unsigned long)hi << 32);
        }
    }

    float mrun[4] = {-1e38f, -1e38f, -1e38f, -1e38f};
    float b1L[4]  = {-1e38f, -1e38f, -1e38f, -1e38f};
    float b2L[4]  = {-1e38f, -1e38f, -1e38f, -1e38f};
    int   b1C[4]  = {0, 0, 0, 0};
    int   b2C[4]  = {0, 0, 0, 0};

    const int sz = c16 & 7;

    auto stage = [&](int b, int ct) {
        const unsigned char* gc = cbf8 + ((size_t)g0 + (size_t)ct * KC) * DD;
#pragma unroll
        for (int r = 0; r < 8; ++r)
            gload_lds16(gc + r * 4096 + tid * 16, &sC[b][0] + r * 4096 + tid * 16);
        if (w == 0)
            gload_lds4((const char*)(esqp + g0 + ct * KC) + lane * 4,
                       (char*)&sEsq[b][0] + lane * 4);
    };

    // track only in the main loop (prepass re-scans chunk 0: double-tracking
    // would duplicate chunk-0 tops into b2 -- the round-6 bug).
    auto scan_chunk = [&](int cur, int gbase, bool append, bool track) {
        float thr[4], ml[4];
#pragma unroll
        for (int cg = 0; cg < 4; ++cg) { thr[cg] = mrun[cg] - TH2; ml[cg] = -1e38f; }
#pragma unroll 1
        for (int ct = 0; ct < 4; ++ct) {
            const int crow = ct * 16 + c16;
            const unsigned char* base = &sC[cur][crow * DD];
            u64x2 a[8];
#pragma unroll
            for (int p = 0; p < 8; ++p)
                a[p] = *reinterpret_cast<const u64x2*>(base + ((p * 4 + ub) ^ sz) * 16);
            f32x4 ep = *reinterpret_cast<const f32x4*>(&sEsq[cur][ct * 16 + ub * 4]);
#pragma unroll
            for (int cg = 0; cg < 4; ++cg) {
                f32x4 acc = {0.f, 0.f, 0.f, 0.f};
#pragma unroll
                for (int p = 0; p < 8; ++p) {
                    acc = mfma8(a[p].x, hf[cg][2 * p],     acc);
                    acc = mfma8(a[p].y, hf[cg][2 * p + 1], acc);
                }
                float Lv[4];
#pragma unroll
                for (int r = 0; r < 4; ++r) Lv[r] = fmaf(acc[r], SC_CROSS, -ep[r]);
                if (track) {
#pragma unroll
                    for (int r = 0; r < 4; ++r) {
                        const int cd = gbase + ct * 16 + ub * 4 + r;
                        if (Lv[r] > b1L[cg])      { b2L[cg] = b1L[cg]; b2C[cg] = b1C[cg];
                                                    b1L[cg] = Lv[r];   b1C[cg] = cd; }
                        else if (Lv[r] > b2L[cg]) { b2L[cg] = Lv[r];   b2C[cg] = cd; }
                    }
                }
                if (append) {
                    if (Lv[0] > thr[cg] || Lv[1] > thr[cg] ||
                        Lv[2] > thr[cg] || Lv[3] > thr[cg]) {
                        const int rowloc = w * 64 + cg * 16 + c16;
                        const size_t lb = ((size_t)(qb + rowloc) * NSUB + oct) * CAPS;
#pragma unroll
                        for (int r = 0; r < 4; ++r)
                            if (Lv[r] > thr[cg]) {
                                int idx  = atomicAdd(&sCnt[rowloc], 1);
                                int slot = idx < CAPS ? idx
                                         : NPROT + ((idx - NPROT) & (NPROT - 1));
                                wlist[lb + slot] = packE(Lv[r], gbase + ct * 16 + ub * 4 + r);
                            }
                    }
                }
                float m4 = fmaxf(fmaxf(Lv[0], Lv[1]), fmaxf(Lv[2], Lv[3]));
                ml[cg] = fmaxf(ml[cg], m4);
            }
        }
#pragma unroll
        for (int cg = 0; cg < 4; ++cg) {
            float m = ml[cg];
            m = fmaxf(m, __shfl_xor(m, 16));
            m = fmaxf(m, __shfl_xor(m, 32));
            mrun[cg] = fmaxf(mrun[cg], m);
        }
    };

    // prologue: stage chunk 0; prime running max (no append, no tracking)
    stage(0, 0);
    __syncthreads();
    scan_chunk(0, g0, false, false);

    int cur = 0;
    for (int t = 0; t < NCHUNK; ++t) {
        if (t + 1 < NCHUNK) stage(cur ^ 1, t + 1);
        scan_chunk(cur, g0 + t * KC, true, true);
        __syncthreads();
        cur ^= 1;
    }

    // protected slots: per cg row, owning lane ub writes its top-2
#pragma unroll
    for (int cg = 0; cg < 4; ++cg) {
        const int rowloc = w * 64 + cg * 16 + c16;
        const size_t lb = ((size_t)(qb + rowloc) * NSUB + oct) * CAPS;
        wlist[lb + ub * 2]     = packE(b1L[cg], b1C[cg]);
        wlist[lb + ub * 2 + 1] = packE(b2L[cg], b2C[cg]);
    }
    if (tid < BQ) wcnt[(size_t)(qb + tid) * NSUB + oct] = (unsigned)sCnt[tid];
}

// ---- K3: merge sub-lists, dedup, prune, exact fp32 softmax gather ----
__global__ __launch_bounds__(512)
void vq_merge_kernel(const float* __restrict__ h,
                     const float* __restrict__ cb,
                     const unsigned int* __restrict__ wlist,
                     const unsigned int* __restrict__ wcnt,
                     float* __restrict__ out)
{
    const int w    = threadIdx.x >> 6;
    const int lane = threadIdx.x & 63;
    const int qg   = blockIdx.x * 8 + w;

    const int sl = lane >> 3;           // sub-list (octant) 0..7
    const int s0 = (lane & 7) * 2;      // slot pair
    const size_t base = ((size_t)qg * NSUB + sl) * CAPS;
    const unsigned cnt   = wcnt[(size_t)qg * NSUB + sl];
    const unsigned limit = cnt < (unsigned)CAPS ? cnt : (unsigned)CAPS;

    uint2 e2 = *reinterpret_cast<const uint2*>(&wlist[base + s0]);
    int   code0 = e2.x & 0xFFFF, code1 = e2.y & 0xFFFF;
    float L0 = __uint_as_float(e2.x & 0xFFFF0000u);
    float L1 = __uint_as_float(e2.y & 0xFFFF0000u);
    bool v0 = (unsigned)s0 < limit;
    bool v1 = (unsigned)(s0 + 1) < limit;
    {
        uint4 p0 = *reinterpret_cast<const uint4*>(&wlist[base]);
        uint4 p1 = *reinterpret_cast<const uint4*>(&wlist[base + 4]);
        const unsigned pc[8] = {p0.x & 0xFFFFu, p0.y & 0xFFFFu, p0.z & 0xFFFFu, p0.w & 0xFFFFu,
                                p1.x & 0xFFFFu, p1.y & 0xFFFFu, p1.z & 0xFFFFu, p1.w & 0xFFFFu};
        const int lim0 = (s0 >= NPROT) ? 8 : s0;
        bool d0 = false, d1 = false;
#pragma unroll
        for (int j = 0; j < 8; ++j) {
            d0 |= (j < lim0) && ((unsigned)code0 == pc[j]);
            d1 |= (j < lim0) && ((unsigned)code1 == pc[j]);
        }
        d1 |= (code1 == code0) && (s0 < NPROT);
        v0 &= !d0; v1 &= !d1;
    }

    float m = fmaxf(v0 ? L0 : -1e38f, v1 ? L1 : -1e38f);
#pragma unroll
    for (int off = 1; off < 64; off <<= 1) m = fmaxf(m, __shfl_xor(m, off));
    const float thr = m - PRUNE;
    unsigned long long mask0 = __ballot(v0 && L0 > thr);
    unsigned long long mask1 = __ballot(v1 && L1 > thr);

    float hreg[8];
    const float* hp = h + (size_t)qg * DD + lane * 8;
#pragma unroll
    for (int j = 0; j < 8; ++j) hreg[j] = hp[j];

    float Mex = -1e38f, lsum = 0.f;
    float acc[8] = {0.f,0.f,0.f,0.f,0.f,0.f,0.f,0.f};

    auto process = [&](unsigned long long mask, int codev) {
#pragma unroll 1
        while (mask) {
            const int s = __builtin_ctzll(mask);
            mask &= mask - 1;
            const int code = __shfl(codev, s);
            const float* cp = cb + (size_t)code * DD + lane * 8;
            float c[8];
            float dot = 0.f, s2 = 0.f;
#pragma unroll
            for (int j = 0; j < 8; ++j) {
                c[j] = cp[j];
                dot += hreg[j] * c[j];
                s2  += c[j] * c[j];
            }
#pragma unroll
            for (int off = 32; off > 0; off >>= 1) {
                dot += __shfl_xor(dot, off);
                s2  += __shfl_xor(s2,  off);
            }
            const float Lex = dot * SC_CROSS - s2 * SC_ESQ;   // exact log2-logit
            const float mn  = fmaxf(Mex, Lex);
            const float f   = exp2f(Mex - mn);
            const float wj  = exp2f(Lex - mn);
            lsum = lsum * f + wj;
#pragma unroll
            for (int j = 0; j < 8; ++j) acc[j] = acc[j] * f + wj * c[j];
            Mex = mn;
        }
    };
    process(mask0, code0);
    process(mask1, code1);

    const float inv = 1.0f / lsum;
    float* op = out + (size_t)qg * DD + lane * 8;
    float4 o0 = {acc[0]*inv, acc[1]*inv, acc[2]*inv, acc[3]*inv};
    float4 o1 = {acc[4]*inv, acc[5]*inv, acc[6]*inv, acc[7]*inv};
    *reinterpret_cast<float4*>(op)     = o0;
    *reinterpret_cast<float4*>(op + 4) = o1;
}

extern "C" void kernel_launch(void* const* d_in, const int* in_sizes, int n_in,
                              void* d_out, int out_size, void* d_ws, size_t ws_size,
                              hipStream_t stream) {
    const float* h  = (const float*)d_in[0];   // (16384, 512) fp32
    const float* cb = (const float*)d_in[1];   // (8192, 512) fp32
    float* out = (float*)d_out;                // (16384, 512) fp32

    // ws: cbf8 4MB | esqp 32KB | wlist 8.4MB | wcnt 512KB  (~12.9 MB)
    char* p = (char*)d_ws;
    unsigned char* cbf8 = (unsigned char*)p;  p += SZ_CBF8;
    float*         esqp = (float*)p;          p += SZ_ESQ;
    unsigned int*  wlist = (unsigned int*)p;  p += SZ_WLIST;
    unsigned int*  wcnt  = (unsigned int*)p;

    vq_convert_cb<<<dim3(NCODES / 8), dim3(256), 0, stream>>>(cb, cbf8, esqp);
    vq_scan_kernel<<<dim3(512), dim3(256), 0, stream>>>(h, cbf8, esqp, wlist, wcnt);
    vq_merge_kernel<<<dim3(16384 / 8), dim3(512), 0, stream>>>(h, cb, wlist, wcnt, out);
}